// Round 1
// baseline (2088.059 us; speedup 1.0000x reference)
//
#include <hip/hip_runtime.h>
#include <math.h>

#define NN 100000
#define EE 800000
#define IN_DIM 128
#define HID 32
#define HEADS 4
#define QKV 128         // HEADS*HID
#define COLS 416        // 3*QKV + HID (q|k|v|skip)
#define OUT_DIM 16

// ---------------- utility: float atomic max via int/uint ----------------
__device__ __forceinline__ void atomicMaxF(float* addr, float val) {
    if (val >= 0.0f) {
        atomicMax((int*)addr, __float_as_int(val));
    } else {
        atomicMin((unsigned int*)addr, __float_as_uint(val));
    }
}

// ---------------- pack weights: Wp[K][416], bp[416] ----------------
__global__ void pack_w(const float* __restrict__ Wq, const float* __restrict__ bq,
                       const float* __restrict__ Wk, const float* __restrict__ bk,
                       const float* __restrict__ Wv, const float* __restrict__ bv,
                       const float* __restrict__ Ws, const float* __restrict__ bs,
                       float* __restrict__ Wp, float* __restrict__ bp, int K) {
    int idx = blockIdx.x * blockDim.x + threadIdx.x;
    int total = K * COLS;
    if (idx < total) {
        int k = idx / COLS;
        int j = idx - k * COLS;
        float v;
        if (j < 128)      v = Wq[k * 128 + j];
        else if (j < 256) v = Wk[k * 128 + (j - 128)];
        else if (j < 384) v = Wv[k * 128 + (j - 256)];
        else              v = Ws[k * 32 + (j - 384)];
        Wp[idx] = v;
    }
    if (idx < COLS) {
        float b;
        if (idx < 128)      b = bq[idx];
        else if (idx < 256) b = bk[idx - 128];
        else if (idx < 384) b = bv[idx - 256];
        else                b = bs[idx - 384];
        bp[idx] = b;
    }
}

// ---------------- init per-layer softmax state ----------------
__global__ void init_layer(float* __restrict__ mbuf, float* __restrict__ sbuf,
                           float* __restrict__ agg) {
    int idx = blockIdx.x * blockDim.x + threadIdx.x;
    int n4 = NN * 4;
    if (idx < n4) {
        mbuf[idx] = -INFINITY;
    } else if (idx < 2 * n4) {
        sbuf[idx - n4] = 0.0f;
    } else if (idx < 2 * n4 + NN * QKV) {
        agg[idx - 2 * n4] = 0.0f;
    }
}

// ---------------- fused qkv+skip GEMM: Out[N][416] = X[N][K] @ Wp + bp ----
// block 256 threads = 16x16, tile 64 rows x 64 cols, microtile 4x4, TK=32
__global__ __launch_bounds__(256) void gemm_qkvs(
        const float* __restrict__ X, const float* __restrict__ Wp,
        const float* __restrict__ bp, float* __restrict__ Out,
        int Nrows, int K) {
    __shared__ float xs[64][36];   // [row][k] padded to 36 (16B-aligned rows)
    __shared__ float ws[32][64];   // [k][col]
    const int tid = threadIdx.x;
    const int tx = tid & 15;       // col group
    const int ty = tid >> 4;       // row group
    const int m0 = blockIdx.x * 64;
    const int n0 = blockIdx.y * 64;

    float acc[4][4] = {};

    for (int kc = 0; kc < K; kc += 32) {
        // load X tile: 64 rows x 32 k -> 512 float4, 2 per thread
        #pragma unroll
        for (int i = 0; i < 2; ++i) {
            int lid = tid + i * 256;
            int r = lid >> 3;
            int c4 = lid & 7;
            float4 xv = make_float4(0.f, 0.f, 0.f, 0.f);
            if (m0 + r < Nrows)
                xv = *(const float4*)(X + (size_t)(m0 + r) * K + kc + c4 * 4);
            *(float4*)&xs[r][c4 * 4] = xv;
        }
        // load W tile: 32 k x 64 cols -> 512 float4, 2 per thread
        #pragma unroll
        for (int i = 0; i < 2; ++i) {
            int lid = tid + i * 256;
            int kr = lid >> 4;
            int c4 = lid & 15;
            int col = n0 + c4 * 4;
            float4 wv = make_float4(0.f, 0.f, 0.f, 0.f);
            if (col < COLS)
                wv = *(const float4*)(Wp + (size_t)(kc + kr) * COLS + col);
            *(float4*)&ws[kr][c4 * 4] = wv;
        }
        __syncthreads();
        #pragma unroll 8
        for (int k = 0; k < 32; ++k) {
            float x0 = xs[ty * 4 + 0][k];
            float x1 = xs[ty * 4 + 1][k];
            float x2 = xs[ty * 4 + 2][k];
            float x3 = xs[ty * 4 + 3][k];
            float4 wv = *(const float4*)&ws[k][tx * 4];
            acc[0][0] += x0 * wv.x; acc[0][1] += x0 * wv.y; acc[0][2] += x0 * wv.z; acc[0][3] += x0 * wv.w;
            acc[1][0] += x1 * wv.x; acc[1][1] += x1 * wv.y; acc[1][2] += x1 * wv.z; acc[1][3] += x1 * wv.w;
            acc[2][0] += x2 * wv.x; acc[2][1] += x2 * wv.y; acc[2][2] += x2 * wv.z; acc[2][3] += x2 * wv.w;
            acc[3][0] += x3 * wv.x; acc[3][1] += x3 * wv.y; acc[3][2] += x3 * wv.z; acc[3][3] += x3 * wv.w;
        }
        __syncthreads();
    }

    int col = n0 + tx * 4;
    if (col < COLS) {
        float4 bv = *(const float4*)(bp + col);
        #pragma unroll
        for (int i = 0; i < 4; ++i) {
            int row = m0 + ty * 4 + i;
            if (row < Nrows) {
                float4 o;
                o.x = acc[i][0] + bv.x;
                o.y = acc[i][1] + bv.y;
                o.z = acc[i][2] + bv.z;
                o.w = acc[i][3] + bv.w;
                *(float4*)(Out + (size_t)row * COLS + col) = o;
            }
        }
    }
}

// ---------------- edge pass 1: alpha + segment max (wave per edge) -------
__global__ __launch_bounds__(256) void edge_alpha(
        const float* __restrict__ qkvs, const int* __restrict__ ei,
        float* __restrict__ alphab, float* __restrict__ mbuf) {
    const int lane = threadIdx.x & 63;
    const int wid = (blockIdx.x * blockDim.x + threadIdx.x) >> 6;
    const int nw = (gridDim.x * blockDim.x) >> 6;
    for (int e = wid; e < EE; e += nw) {
        int src = ei[e];
        int dst = ei[EE + e];
        const float2* qp = (const float2*)(qkvs + (size_t)dst * COLS);
        const float2* kp = (const float2*)(qkvs + (size_t)src * COLS + 128);
        float2 q2 = qp[lane];
        float2 k2 = kp[lane];
        float part = q2.x * k2.x + q2.y * k2.y;
        part += __shfl_xor(part, 1);
        part += __shfl_xor(part, 2);
        part += __shfl_xor(part, 4);
        part += __shfl_xor(part, 8);
        if ((lane & 15) == 0) {
            int h = lane >> 4;
            float a = part * 0.17677669529663687f;  // 1/sqrt(32)
            alphab[(size_t)e * 4 + h] = a;
            atomicMaxF(mbuf + (size_t)dst * 4 + h, a);
        }
    }
}

// ---------------- edge pass 2: p, segment sum, weighted v accumulate ----
__global__ __launch_bounds__(256) void edge_accum(
        const float* __restrict__ qkvs, const int* __restrict__ ei,
        const float* __restrict__ alphab, const float* __restrict__ mbuf,
        float* __restrict__ sbuf, float* __restrict__ agg) {
    const int lane = threadIdx.x & 63;
    const int wid = (blockIdx.x * blockDim.x + threadIdx.x) >> 6;
    const int nw = (gridDim.x * blockDim.x) >> 6;
    for (int e = wid; e < EE; e += nw) {
        int src = ei[e];
        int dst = ei[EE + e];
        float pl = 0.0f;
        if (lane < 4) {
            float a = alphab[(size_t)e * 4 + lane];
            float mm = mbuf[(size_t)dst * 4 + lane];
            pl = __expf(a - mm);
            atomicAdd(sbuf + (size_t)dst * 4 + lane, pl);
        }
        int h = lane >> 4;
        float ph = __shfl(pl, h);
        const float2* vp = (const float2*)(qkvs + (size_t)src * COLS + 256);
        float2 v2 = vp[lane];
        float* ap = agg + (size_t)dst * QKV + lane * 2;
        atomicAdd(ap + 0, ph * v2.x);
        atomicAdd(ap + 1, ph * v2.y);
    }
}

// ---------------- finalize: mean over heads + skip + relu ----------------
__global__ void finalize(const float* __restrict__ agg, const float* __restrict__ sbuf,
                         const float* __restrict__ qkvs, float* __restrict__ hout) {
    int idx = blockIdx.x * blockDim.x + threadIdx.x;
    if (idx >= NN * HID) return;
    int n = idx >> 5;
    int c = idx & 31;
    float accv = 0.0f;
    #pragma unroll
    for (int h = 0; h < HEADS; ++h) {
        float sv = sbuf[n * 4 + h];
        if (sv > 0.0f)
            accv += agg[(size_t)n * QKV + h * 32 + c] / sv;
    }
    float r = accv * 0.25f + qkvs[(size_t)n * COLS + 384 + c];
    hout[idx] = fmaxf(r, 0.0f);   // relu after each conv
}

// ---------------- final linear: out = h @ Wout + bout --------------------
__global__ void out_linear(const float* __restrict__ h, const float* __restrict__ Wout,
                           const float* __restrict__ bout, float* __restrict__ out) {
    int idx = blockIdx.x * blockDim.x + threadIdx.x;
    if (idx >= NN * OUT_DIM) return;
    int n = idx >> 4;
    int j = idx & 15;
    float accv = bout[j];
    #pragma unroll
    for (int k = 0; k < HID; ++k)
        accv += h[(size_t)n * HID + k] * Wout[k * OUT_DIM + j];
    out[idx] = accv;
}

extern "C" void kernel_launch(void* const* d_in, const int* in_sizes, int n_in,
                              void* d_out, int out_size, void* d_ws, size_t ws_size,
                              hipStream_t stream) {
    const float* x  = (const float*)d_in[0];
    const int*   ei = (const int*)d_in[1];
    // layer 0 weights: d_in[2..9], layer 1: d_in[10..17]
    const float* l0w[8]; const float* l1w[8];
    for (int i = 0; i < 8; ++i) { l0w[i] = (const float*)d_in[2 + i]; l1w[i] = (const float*)d_in[10 + i]; }
    const float* Wout = (const float*)d_in[18];
    const float* bout = (const float*)d_in[19];
    float* out = (float*)d_out;

    // workspace layout (floats)
    float* ws = (float*)d_ws;
    float* qkvs   = ws;                          // NN*416
    float* agg    = qkvs + (size_t)NN * COLS;    // NN*128
    float* mbuf   = agg + (size_t)NN * QKV;      // NN*4
    float* sbuf   = mbuf + (size_t)NN * 4;       // NN*4
    float* alphab = sbuf + (size_t)NN * 4;       // EE*4
    float* h0     = alphab + (size_t)EE * 4;     // NN*32
    float* Wp0    = h0 + (size_t)NN * HID;       // 128*416
    float* bp0    = Wp0 + 128 * COLS;            // 416
    float* Wp1    = bp0 + COLS;                  // 32*416
    float* bp1    = Wp1 + 32 * COLS;             // 416

    // pack weights
    pack_w<<<(128 * COLS + 255) / 256, 256, 0, stream>>>(
        l0w[0], l0w[1], l0w[2], l0w[3], l0w[4], l0w[5], l0w[6], l0w[7], Wp0, bp0, 128);
    pack_w<<<(32 * COLS + 255) / 256, 256, 0, stream>>>(
        l1w[0], l1w[1], l1w[2], l1w[3], l1w[4], l1w[5], l1w[6], l1w[7], Wp1, bp1, 32);

    dim3 gemm_grid0((NN + 63) / 64, (COLS + 63) / 64);
    int init_blocks = (NN * (8 + QKV) + 255) / 256;

    // ---------------- layer 0 ----------------
    init_layer<<<init_blocks, 256, 0, stream>>>(mbuf, sbuf, agg);
    gemm_qkvs<<<gemm_grid0, 256, 0, stream>>>(x, Wp0, bp0, qkvs, NN, 128);
    edge_alpha<<<2048, 256, 0, stream>>>(qkvs, ei, alphab, mbuf);
    edge_accum<<<2048, 256, 0, stream>>>(qkvs, ei, alphab, mbuf, sbuf, agg);
    finalize<<<(NN * HID + 255) / 256, 256, 0, stream>>>(agg, sbuf, qkvs, h0);

    // ---------------- layer 1 ----------------
    init_layer<<<init_blocks, 256, 0, stream>>>(mbuf, sbuf, agg);
    gemm_qkvs<<<gemm_grid0, 256, 0, stream>>>(h0, Wp1, bp1, qkvs, NN, 32);
    edge_alpha<<<2048, 256, 0, stream>>>(qkvs, ei, alphab, mbuf);
    edge_accum<<<2048, 256, 0, stream>>>(qkvs, ei, alphab, mbuf, sbuf, agg);
    finalize<<<(NN * HID + 255) / 256, 256, 0, stream>>>(agg, sbuf, qkvs, h0);

    // ---------------- output linear ----------------
    out_linear<<<(NN * OUT_DIM + 255) / 256, 256, 0, stream>>>(h0, Wout, bout, out);
}

// Round 2
// 658.478 us; speedup vs baseline: 3.1710x; 3.1710x over previous
//
#include <hip/hip_runtime.h>
#include <math.h>

#define NN 100000
#define EE 800000
#define IN_DIM 128
#define HID 32
#define HEADS 4
#define QKV 128         // HEADS*HID
#define COLS 416        // 3*QKV + HID (q|k|v|skip)
#define OUT_DIM 16
#define NB 98           // ceil(NN/1024) scan blocks

// ---------------- pack weights: Wp[K][416], bp[416] ----------------
__global__ void pack_w(const float* __restrict__ Wq, const float* __restrict__ bq,
                       const float* __restrict__ Wk, const float* __restrict__ bk,
                       const float* __restrict__ Wv, const float* __restrict__ bv,
                       const float* __restrict__ Ws, const float* __restrict__ bs,
                       float* __restrict__ Wp, float* __restrict__ bp, int K) {
    int idx = blockIdx.x * blockDim.x + threadIdx.x;
    int total = K * COLS;
    if (idx < total) {
        int k = idx / COLS;
        int j = idx - k * COLS;
        float v;
        if (j < 128)      v = Wq[k * 128 + j];
        else if (j < 256) v = Wk[k * 128 + (j - 128)];
        else if (j < 384) v = Wv[k * 128 + (j - 256)];
        else              v = Ws[k * 32 + (j - 384)];
        Wp[idx] = v;
    }
    if (idx < COLS) {
        float b;
        if (idx < 128)      b = bq[idx];
        else if (idx < 256) b = bk[idx - 128];
        else if (idx < 384) b = bv[idx - 256];
        else                b = bs[idx - 384];
        bp[idx] = b;
    }
}

// ---------------- CSR build ----------------
__global__ void zero_deg(int* __restrict__ deg) {
    int i = blockIdx.x * blockDim.x + threadIdx.x;
    if (i < NN) deg[i] = 0;
}

__global__ void hist_dst(const int* __restrict__ ei, int* __restrict__ deg) {
    int e = blockIdx.x * blockDim.x + threadIdx.x;
    if (e < EE) atomicAdd(&deg[ei[EE + e]], 1);
}

// per-block (1024 elems) total
__global__ void block_sum(const int* __restrict__ deg, int* __restrict__ partial) {
    __shared__ int sdata[256];
    int b = blockIdx.x, t = threadIdx.x;
    int sum = 0;
    for (int i = t; i < 1024; i += 256) {
        int g = b * 1024 + i;
        if (g < NN) sum += deg[g];
    }
    sdata[t] = sum; __syncthreads();
    for (int s = 128; s > 0; s >>= 1) {
        if (t < s) sdata[t] += sdata[t + s];
        __syncthreads();
    }
    if (t == 0) partial[b] = sdata[0];
}

__global__ void scan_partial(int* __restrict__ partial) {
    if (blockIdx.x == 0 && threadIdx.x == 0) {
        int run = 0;
        for (int i = 0; i < NB; ++i) { int v = partial[i]; partial[i] = run; run += v; }
    }
}

__global__ void block_scan(const int* __restrict__ deg, const int* __restrict__ partial,
                           int* __restrict__ roff, int* __restrict__ woff) {
    __shared__ int ssum[256];
    int b = blockIdx.x, t = threadIdx.x;
    int base = b * 1024 + t * 4;
    int v[4]; int s = 0;
    #pragma unroll
    for (int i = 0; i < 4; ++i) {
        int g = base + i;
        v[i] = (g < NN) ? deg[g] : 0;
        s += v[i];
    }
    ssum[t] = s; __syncthreads();
    for (int off = 1; off < 256; off <<= 1) {
        int val = (t >= off) ? ssum[t - off] : 0;
        __syncthreads();
        ssum[t] += val;
        __syncthreads();
    }
    int excl = (t == 0) ? 0 : ssum[t - 1];
    excl += partial[b];
    #pragma unroll
    for (int i = 0; i < 4; ++i) {
        int g = base + i;
        if (g < NN) { roff[g] = excl; woff[g] = excl; }
        excl += v[i];
    }
    if (b == NB - 1 && t == 255) roff[NN] = EE;
}

__global__ void scatter_edges(const int* __restrict__ ei, int* __restrict__ woff,
                              int* __restrict__ esrc) {
    int e = blockIdx.x * blockDim.x + threadIdx.x;
    if (e < EE) {
        int dst = ei[EE + e];
        int pos = atomicAdd(&woff[dst], 1);
        esrc[pos] = ei[e];
    }
}

// ---------------- fused qkv+skip GEMM: Out[N][416] = X[N][K] @ Wp + bp ----
__global__ __launch_bounds__(256) void gemm_qkvs(
        const float* __restrict__ X, const float* __restrict__ Wp,
        const float* __restrict__ bp, float* __restrict__ Out,
        int Nrows, int K) {
    __shared__ float xs[64][36];
    __shared__ float ws[32][64];
    const int tid = threadIdx.x;
    const int tx = tid & 15;
    const int ty = tid >> 4;
    const int m0 = blockIdx.x * 64;
    const int n0 = blockIdx.y * 64;

    float acc[4][4] = {};

    for (int kc = 0; kc < K; kc += 32) {
        #pragma unroll
        for (int i = 0; i < 2; ++i) {
            int lid = tid + i * 256;
            int r = lid >> 3;
            int c4 = lid & 7;
            float4 xv = make_float4(0.f, 0.f, 0.f, 0.f);
            if (m0 + r < Nrows)
                xv = *(const float4*)(X + (size_t)(m0 + r) * K + kc + c4 * 4);
            *(float4*)&xs[r][c4 * 4] = xv;
        }
        #pragma unroll
        for (int i = 0; i < 2; ++i) {
            int lid = tid + i * 256;
            int kr = lid >> 4;
            int c4 = lid & 15;
            int col = n0 + c4 * 4;
            float4 wv = make_float4(0.f, 0.f, 0.f, 0.f);
            if (col < COLS)
                wv = *(const float4*)(Wp + (size_t)(kc + kr) * COLS + col);
            *(float4*)&ws[kr][c4 * 4] = wv;
        }
        __syncthreads();
        #pragma unroll 8
        for (int k = 0; k < 32; ++k) {
            float x0 = xs[ty * 4 + 0][k];
            float x1 = xs[ty * 4 + 1][k];
            float x2 = xs[ty * 4 + 2][k];
            float x3 = xs[ty * 4 + 3][k];
            float4 wv = *(const float4*)&ws[k][tx * 4];
            acc[0][0] += x0 * wv.x; acc[0][1] += x0 * wv.y; acc[0][2] += x0 * wv.z; acc[0][3] += x0 * wv.w;
            acc[1][0] += x1 * wv.x; acc[1][1] += x1 * wv.y; acc[1][2] += x1 * wv.z; acc[1][3] += x1 * wv.w;
            acc[2][0] += x2 * wv.x; acc[2][1] += x2 * wv.y; acc[2][2] += x2 * wv.z; acc[2][3] += x2 * wv.w;
            acc[3][0] += x3 * wv.x; acc[3][1] += x3 * wv.y; acc[3][2] += x3 * wv.z; acc[3][3] += x3 * wv.w;
        }
        __syncthreads();
    }

    int col = n0 + tx * 4;
    if (col < COLS) {
        float4 bv = *(const float4*)(bp + col);
        #pragma unroll
        for (int i = 0; i < 4; ++i) {
            int row = m0 + ty * 4 + i;
            if (row < Nrows) {
                float4 o;
                o.x = acc[i][0] + bv.x;
                o.y = acc[i][1] + bv.y;
                o.z = acc[i][2] + bv.z;
                o.w = acc[i][3] + bv.w;
                *(float4*)(Out + (size_t)row * COLS + col) = o;
            }
        }
    }
}

// ---------------- fused attention: one wave per dst node ----------------
// lanes 0..31: q fragment (float4 = 4 channels, head = kl>>3)
// lanes 32..63: v accumulator (float4), head = kl>>3; kl = lane&31
// per edge: one wave-wide float4 gather of the contiguous k|v region (1 KB)
__global__ __launch_bounds__(256) void fused_attn(
        const float* __restrict__ qkvs, const int* __restrict__ roff,
        const int* __restrict__ esrc, float* __restrict__ hout) {
    const int lane = threadIdx.x & 63;
    const int w = (blockIdx.x * blockDim.x + threadIdx.x) >> 6;
    if (w >= NN) return;
    const int n = w;
    const int kl = lane & 31;
    const int hsrc = kl & 24;                 // leader lane (0..31) of this head group
    const float* row = qkvs + (size_t)n * COLS;
    // lanes 0..31 load q; lanes 32..39 load skip (reused in epilogue); 40..63 harmless dup
    const float* qaddr = (lane < 32) ? (row + 4 * kl) : (row + 384 + 4 * (kl & 7));
    float4 q4 = *(const float4*)qaddr;

    float m = -INFINITY, s = 0.f;
    float4 acc = make_float4(0.f, 0.f, 0.f, 0.f);
    const int e0 = roff[n], e1 = roff[n + 1];
    int src_next = (e0 < e1) ? esrc[e0] : 0;
    for (int e = e0; e < e1; ++e) {
        int src = src_next;
        if (e + 1 < e1) src_next = esrc[e + 1];
        const float* kvrow = qkvs + (size_t)src * COLS + 128;
        float4 kv = *(const float4*)(kvrow + 4 * lane);   // lanes<32: k, lanes>=32: v
        float part = q4.x * kv.x + q4.y * kv.y + q4.z * kv.z + q4.w * kv.w;
        part += __shfl_xor(part, 1);
        part += __shfl_xor(part, 2);
        part += __shfl_xor(part, 4);
        float a = __shfl(part, hsrc) * 0.17677669529663687f;  // 1/sqrt(32)
        float mn = fmaxf(m, a);
        float corr = __expf(m - mn);   // first iter: exp(-inf)=0
        float p = __expf(a - mn);
        s = s * corr + p;
        acc.x = acc.x * corr + p * kv.x;
        acc.y = acc.y * corr + p * kv.y;
        acc.z = acc.z * corr + p * kv.z;
        acc.w = acc.w * corr + p * kv.w;
        m = mn;
    }
    float inv = (s > 0.f) ? 1.f / s : 0.f;
    float4 o;
    o.x = acc.x * inv; o.y = acc.y * inv; o.z = acc.z * inv; o.w = acc.w * inv;
    // sum over heads (head bits of kl are bits 3,4 -> xor 8, 16 stays within v-lanes)
    o.x += __shfl_xor(o.x, 8);  o.y += __shfl_xor(o.y, 8);  o.z += __shfl_xor(o.z, 8);  o.w += __shfl_xor(o.w, 8);
    o.x += __shfl_xor(o.x, 16); o.y += __shfl_xor(o.y, 16); o.z += __shfl_xor(o.z, 16); o.w += __shfl_xor(o.w, 16);
    if (lane >= 32 && lane < 40) {
        float4 r;
        r.x = fmaxf(o.x * 0.25f + q4.x, 0.f);   // q4 holds skip in these lanes
        r.y = fmaxf(o.y * 0.25f + q4.y, 0.f);
        r.z = fmaxf(o.z * 0.25f + q4.z, 0.f);
        r.w = fmaxf(o.w * 0.25f + q4.w, 0.f);
        *(float4*)(hout + (size_t)n * HID + 4 * (lane - 32)) = r;
    }
}

// ---------------- final linear: out = h @ Wout + bout --------------------
__global__ void out_linear(const float* __restrict__ h, const float* __restrict__ Wout,
                           const float* __restrict__ bout, float* __restrict__ out) {
    int idx = blockIdx.x * blockDim.x + threadIdx.x;
    if (idx >= NN * OUT_DIM) return;
    int n = idx >> 4;
    int j = idx & 15;
    float accv = bout[j];
    #pragma unroll
    for (int k = 0; k < HID; ++k)
        accv += h[(size_t)n * HID + k] * Wout[k * OUT_DIM + j];
    out[idx] = accv;
}

extern "C" void kernel_launch(void* const* d_in, const int* in_sizes, int n_in,
                              void* d_out, int out_size, void* d_ws, size_t ws_size,
                              hipStream_t stream) {
    const float* x  = (const float*)d_in[0];
    const int*   ei = (const int*)d_in[1];
    const float* l0w[8]; const float* l1w[8];
    for (int i = 0; i < 8; ++i) { l0w[i] = (const float*)d_in[2 + i]; l1w[i] = (const float*)d_in[10 + i]; }
    const float* Wout = (const float*)d_in[18];
    const float* bout = (const float*)d_in[19];
    float* out = (float*)d_out;

    // workspace layout
    float* ws = (float*)d_ws;
    float* qkvs = ws;                           // NN*416 floats
    float* h0   = qkvs + (size_t)NN * COLS;     // NN*32
    float* Wp0  = h0 + (size_t)NN * HID;        // 128*416
    float* bp0  = Wp0 + 128 * COLS;             // 416
    float* Wp1  = bp0 + COLS;                   // 32*416
    float* bp1  = Wp1 + 32 * COLS;              // 416
    int* ibase  = (int*)(bp1 + COLS);
    int* deg     = ibase;                       // NN
    int* roff    = deg + NN;                    // NN+1
    int* woff    = roff + NN + 1;               // NN
    int* partial = woff + NN;                   // NB
    int* esrc    = partial + NB;                // EE

    // pack weights
    pack_w<<<(128 * COLS + 255) / 256, 256, 0, stream>>>(
        l0w[0], l0w[1], l0w[2], l0w[3], l0w[4], l0w[5], l0w[6], l0w[7], Wp0, bp0, 128);
    pack_w<<<(32 * COLS + 255) / 256, 256, 0, stream>>>(
        l1w[0], l1w[1], l1w[2], l1w[3], l1w[4], l1w[5], l1w[6], l1w[7], Wp1, bp1, 32);

    // CSR build (once; reused by both layers)
    zero_deg<<<(NN + 255) / 256, 256, 0, stream>>>(deg);
    hist_dst<<<(EE + 255) / 256, 256, 0, stream>>>(ei, deg);
    block_sum<<<NB, 256, 0, stream>>>(deg, partial);
    scan_partial<<<1, 64, 0, stream>>>(partial);
    block_scan<<<NB, 256, 0, stream>>>(deg, partial, roff, woff);
    scatter_edges<<<(EE + 255) / 256, 256, 0, stream>>>(ei, woff, esrc);

    dim3 gemm_grid((NN + 63) / 64, (COLS + 63) / 64);
    int attn_blocks = (NN * 64 + 255) / 256;   // one wave per node

    // layer 0
    gemm_qkvs<<<gemm_grid, 256, 0, stream>>>(x, Wp0, bp0, qkvs, NN, 128);
    fused_attn<<<attn_blocks, 256, 0, stream>>>(qkvs, roff, esrc, h0);

    // layer 1
    gemm_qkvs<<<gemm_grid, 256, 0, stream>>>(h0, Wp1, bp1, qkvs, NN, 32);
    fused_attn<<<attn_blocks, 256, 0, stream>>>(qkvs, roff, esrc, h0);

    // output linear
    out_linear<<<(NN * OUT_DIM + 255) / 256, 256, 0, stream>>>(h0, Wout, bout, out);
}

// Round 3
// 644.633 us; speedup vs baseline: 3.2391x; 1.0215x over previous
//
#include <hip/hip_runtime.h>
#include <math.h>

#define NN 100000
#define EE 800000
#define IN_DIM 128
#define HID 32
#define HEADS 4
#define QKV 128         // HEADS*HID
#define COLS 416        // 3*QKV + HID (q|k|v|skip)
#define OUT_DIM 16
#define NB 98           // ceil(NN/1024) scan blocks

// ---------------- pack weights: Wp[K][416], bp[416] ----------------
__global__ void pack_w(const float* __restrict__ Wq, const float* __restrict__ bq,
                       const float* __restrict__ Wk, const float* __restrict__ bk,
                       const float* __restrict__ Wv, const float* __restrict__ bv,
                       const float* __restrict__ Ws, const float* __restrict__ bs,
                       float* __restrict__ Wp, float* __restrict__ bp, int K) {
    int idx = blockIdx.x * blockDim.x + threadIdx.x;
    int total = K * COLS;
    if (idx < total) {
        int k = idx / COLS;
        int j = idx - k * COLS;
        float v;
        if (j < 128)      v = Wq[k * 128 + j];
        else if (j < 256) v = Wk[k * 128 + (j - 128)];
        else if (j < 384) v = Wv[k * 128 + (j - 256)];
        else              v = Ws[k * 32 + (j - 384)];
        Wp[idx] = v;
    }
    if (idx < COLS) {
        float b;
        if (idx < 128)      b = bq[idx];
        else if (idx < 256) b = bk[idx - 128];
        else if (idx < 384) b = bv[idx - 256];
        else                b = bs[idx - 384];
        bp[idx] = b;
    }
}

// ---------------- CSR build ----------------
__global__ void zero_deg(int* __restrict__ deg) {
    int i = blockIdx.x * blockDim.x + threadIdx.x;
    if (i < NN) deg[i] = 0;
}

__global__ void hist_dst(const int* __restrict__ ei, int* __restrict__ deg) {
    int e = blockIdx.x * blockDim.x + threadIdx.x;
    if (e < EE) atomicAdd(&deg[ei[EE + e]], 1);
}

__global__ void block_sum(const int* __restrict__ deg, int* __restrict__ partial) {
    __shared__ int sdata[256];
    int b = blockIdx.x, t = threadIdx.x;
    int sum = 0;
    for (int i = t; i < 1024; i += 256) {
        int g = b * 1024 + i;
        if (g < NN) sum += deg[g];
    }
    sdata[t] = sum; __syncthreads();
    for (int s = 128; s > 0; s >>= 1) {
        if (t < s) sdata[t] += sdata[t + s];
        __syncthreads();
    }
    if (t == 0) partial[b] = sdata[0];
}

__global__ void scan_partial(int* __restrict__ partial) {
    if (blockIdx.x == 0 && threadIdx.x == 0) {
        int run = 0;
        for (int i = 0; i < NB; ++i) { int v = partial[i]; partial[i] = run; run += v; }
    }
}

__global__ void block_scan(const int* __restrict__ deg, const int* __restrict__ partial,
                           int* __restrict__ roff, int* __restrict__ woff) {
    __shared__ int ssum[256];
    int b = blockIdx.x, t = threadIdx.x;
    int base = b * 1024 + t * 4;
    int v[4]; int s = 0;
    #pragma unroll
    for (int i = 0; i < 4; ++i) {
        int g = base + i;
        v[i] = (g < NN) ? deg[g] : 0;
        s += v[i];
    }
    ssum[t] = s; __syncthreads();
    for (int off = 1; off < 256; off <<= 1) {
        int val = (t >= off) ? ssum[t - off] : 0;
        __syncthreads();
        ssum[t] += val;
        __syncthreads();
    }
    int excl = (t == 0) ? 0 : ssum[t - 1];
    excl += partial[b];
    #pragma unroll
    for (int i = 0; i < 4; ++i) {
        int g = base + i;
        if (g < NN) { roff[g] = excl; woff[g] = excl; }
        excl += v[i];
    }
    if (b == NB - 1 && t == 255) roff[NN] = EE;
}

__global__ void scatter_edges(const int* __restrict__ ei, int* __restrict__ woff,
                              int* __restrict__ esrc) {
    int e = blockIdx.x * blockDim.x + threadIdx.x;
    if (e < EE) {
        int dst = ei[EE + e];
        int pos = atomicAdd(&woff[dst], 1);
        esrc[pos] = ei[e];
    }
}

// ---------------- fused qkv+skip GEMM: Out[N][416] = X[N][K] @ Wp + bp ----
// tile 128x64, block 256 = 16 row-groups x 16 col-groups, microtile 8x4.
// X tile stored TRANSPOSED in LDS so inner loop is pure ds_read_b128.
// XCD-aware swizzle: all 7 col-blocks of a row-block -> same XCD (b%8).
__global__ __launch_bounds__(256) void gemm_qkvs(
        const float* __restrict__ X, const float* __restrict__ Wp,
        const float* __restrict__ bp, float* __restrict__ Out,
        int Nrows, int K) {
    __shared__ float xs_t[32][132];   // [k][row], pad 132 to spread store banks
    __shared__ float wsm[32][64];     // [k][col]
    const int tid = threadIdx.x;
    const int tx = tid & 15;          // col group (4 cols)
    const int ty = tid >> 4;          // row group (8 rows)

    const int RB = (Nrows + 127) >> 7;
    int b = blockIdx.x;
    int r = (b & 7) + ((b / 56) << 3);
    int c = (b >> 3) % 7;
    if (r >= RB) return;
    const int m0 = r << 7;
    const int n0 = c << 6;

    float acc[8][4] = {};

    for (int kc = 0; kc < K; kc += 32) {
        // X tile: 128 rows x 32 k = 1024 float4, transposed store
        #pragma unroll
        for (int i = 0; i < 4; ++i) {
            int lid = tid + i * 256;
            int rr = lid >> 3;         // 0..127
            int c4 = lid & 7;          // 0..7
            float4 xv = make_float4(0.f, 0.f, 0.f, 0.f);
            if (m0 + rr < Nrows)
                xv = *(const float4*)(X + (size_t)(m0 + rr) * K + kc + c4 * 4);
            int kk = c4 * 4;
            xs_t[kk + 0][rr] = xv.x;
            xs_t[kk + 1][rr] = xv.y;
            xs_t[kk + 2][rr] = xv.z;
            xs_t[kk + 3][rr] = xv.w;
        }
        // W tile: 32 k x 64 cols = 512 float4
        #pragma unroll
        for (int i = 0; i < 2; ++i) {
            int lid = tid + i * 256;
            int kr = lid >> 4;
            int c4 = lid & 15;
            int col = n0 + c4 * 4;
            float4 wv = make_float4(0.f, 0.f, 0.f, 0.f);
            if (col < COLS)
                wv = *(const float4*)(Wp + (size_t)(kc + kr) * COLS + col);
            *(float4*)&wsm[kr][c4 * 4] = wv;
        }
        __syncthreads();
        #pragma unroll 8
        for (int k = 0; k < 32; ++k) {
            float4 xa = *(const float4*)&xs_t[k][ty * 8];
            float4 xb = *(const float4*)&xs_t[k][ty * 8 + 4];
            float4 wv = *(const float4*)&wsm[k][tx * 4];
            float xr[8] = {xa.x, xa.y, xa.z, xa.w, xb.x, xb.y, xb.z, xb.w};
            #pragma unroll
            for (int i = 0; i < 8; ++i) {
                acc[i][0] += xr[i] * wv.x;
                acc[i][1] += xr[i] * wv.y;
                acc[i][2] += xr[i] * wv.z;
                acc[i][3] += xr[i] * wv.w;
            }
        }
        __syncthreads();
    }

    int col = n0 + tx * 4;
    if (col < COLS) {
        float4 bv = *(const float4*)(bp + col);
        #pragma unroll
        for (int i = 0; i < 8; ++i) {
            int row = m0 + ty * 8 + i;
            if (row < Nrows) {
                float4 o;
                o.x = acc[i][0] + bv.x;
                o.y = acc[i][1] + bv.y;
                o.z = acc[i][2] + bv.z;
                o.w = acc[i][3] + bv.w;
                *(float4*)(Out + (size_t)row * COLS + col) = o;
            }
        }
    }
}

// ---------------- fused attention: one wave per dst node ----------------
// lanes 0..31: q fragment (float4); lanes 32..63: v accumulator (float4).
// 4-edge batching for memory-level parallelism on the kv gathers.
#define ATTN_STEP(kv)  {                                                     \
    float part = q4.x * (kv).x + q4.y * (kv).y + q4.z * (kv).z + q4.w * (kv).w; \
    part += __shfl_xor(part, 1);                                             \
    part += __shfl_xor(part, 2);                                             \
    part += __shfl_xor(part, 4);                                             \
    float a = __shfl(part, hsrc) * 0.17677669529663687f;                     \
    float mn = fmaxf(m, a);                                                  \
    float corr = __expf(m - mn);                                             \
    float p = __expf(a - mn);                                                \
    s = s * corr + p;                                                        \
    acc.x = acc.x * corr + p * (kv).x;                                       \
    acc.y = acc.y * corr + p * (kv).y;                                       \
    acc.z = acc.z * corr + p * (kv).z;                                       \
    acc.w = acc.w * corr + p * (kv).w;                                       \
    m = mn; }

__global__ __launch_bounds__(256) void fused_attn(
        const float* __restrict__ qkvs, const int* __restrict__ roff,
        const int* __restrict__ esrc, float* __restrict__ hout) {
    const int lane = threadIdx.x & 63;
    const int w = (blockIdx.x * blockDim.x + threadIdx.x) >> 6;
    if (w >= NN) return;
    const int n = w;
    const int kl = lane & 31;
    const int hsrc = kl & 24;                 // leader lane of this head group
    const float* row = qkvs + (size_t)n * COLS;
    const float* qaddr = (lane < 32) ? (row + 4 * kl) : (row + 384 + 4 * (kl & 7));
    float4 q4 = *(const float4*)qaddr;

    float m = -INFINITY, s = 0.f;
    float4 acc = make_float4(0.f, 0.f, 0.f, 0.f);
    const int e0 = roff[n], e1 = roff[n + 1];
    int e = e0;
    for (; e + 4 <= e1; e += 4) {
        int s0 = esrc[e], s1 = esrc[e + 1], s2 = esrc[e + 2], s3 = esrc[e + 3];
        float4 kv0 = *(const float4*)(qkvs + (size_t)s0 * COLS + 128 + 4 * lane);
        float4 kv1 = *(const float4*)(qkvs + (size_t)s1 * COLS + 128 + 4 * lane);
        float4 kv2 = *(const float4*)(qkvs + (size_t)s2 * COLS + 128 + 4 * lane);
        float4 kv3 = *(const float4*)(qkvs + (size_t)s3 * COLS + 128 + 4 * lane);
        ATTN_STEP(kv0); ATTN_STEP(kv1); ATTN_STEP(kv2); ATTN_STEP(kv3);
    }
    for (; e < e1; ++e) {
        int sj = esrc[e];
        float4 kv = *(const float4*)(qkvs + (size_t)sj * COLS + 128 + 4 * lane);
        ATTN_STEP(kv);
    }
    float inv = (s > 0.f) ? 1.f / s : 0.f;
    float4 o;
    o.x = acc.x * inv; o.y = acc.y * inv; o.z = acc.z * inv; o.w = acc.w * inv;
    // sum over heads (head bits of kl are bits 3,4)
    o.x += __shfl_xor(o.x, 8);  o.y += __shfl_xor(o.y, 8);  o.z += __shfl_xor(o.z, 8);  o.w += __shfl_xor(o.w, 8);
    o.x += __shfl_xor(o.x, 16); o.y += __shfl_xor(o.y, 16); o.z += __shfl_xor(o.z, 16); o.w += __shfl_xor(o.w, 16);
    if (lane >= 32 && lane < 40) {
        float4 rr;
        rr.x = fmaxf(o.x * 0.25f + q4.x, 0.f);   // q4 holds skip in these lanes
        rr.y = fmaxf(o.y * 0.25f + q4.y, 0.f);
        rr.z = fmaxf(o.z * 0.25f + q4.z, 0.f);
        rr.w = fmaxf(o.w * 0.25f + q4.w, 0.f);
        *(float4*)(hout + (size_t)n * HID + 4 * (lane - 32)) = rr;
    }
}

// ---------------- final linear: out = h @ Wout + bout --------------------
__global__ void out_linear(const float* __restrict__ h, const float* __restrict__ Wout,
                           const float* __restrict__ bout, float* __restrict__ out) {
    int idx = blockIdx.x * blockDim.x + threadIdx.x;
    if (idx >= NN * OUT_DIM) return;
    int n = idx >> 4;
    int j = idx & 15;
    float accv = bout[j];
    #pragma unroll
    for (int k = 0; k < HID; ++k)
        accv += h[(size_t)n * HID + k] * Wout[k * OUT_DIM + j];
    out[idx] = accv;
}

extern "C" void kernel_launch(void* const* d_in, const int* in_sizes, int n_in,
                              void* d_out, int out_size, void* d_ws, size_t ws_size,
                              hipStream_t stream) {
    const float* x  = (const float*)d_in[0];
    const int*   ei = (const int*)d_in[1];
    const float* l0w[8]; const float* l1w[8];
    for (int i = 0; i < 8; ++i) { l0w[i] = (const float*)d_in[2 + i]; l1w[i] = (const float*)d_in[10 + i]; }
    const float* Wout = (const float*)d_in[18];
    const float* bout = (const float*)d_in[19];
    float* out = (float*)d_out;

    // workspace layout
    float* ws = (float*)d_ws;
    float* qkvs = ws;                           // NN*416 floats
    float* h0   = qkvs + (size_t)NN * COLS;     // NN*32
    float* Wp0  = h0 + (size_t)NN * HID;        // 128*416
    float* bp0  = Wp0 + 128 * COLS;             // 416
    float* Wp1  = bp0 + COLS;                   // 32*416
    float* bp1  = Wp1 + 32 * COLS;              // 416
    int* ibase  = (int*)(bp1 + COLS);
    int* deg     = ibase;                       // NN
    int* roff    = deg + NN;                    // NN+1
    int* woff    = roff + NN + 1;               // NN
    int* partial = woff + NN;                   // NB
    int* esrc    = partial + NB;                // EE

    // pack weights
    pack_w<<<(128 * COLS + 255) / 256, 256, 0, stream>>>(
        l0w[0], l0w[1], l0w[2], l0w[3], l0w[4], l0w[5], l0w[6], l0w[7], Wp0, bp0, 128);
    pack_w<<<(32 * COLS + 255) / 256, 256, 0, stream>>>(
        l1w[0], l1w[1], l1w[2], l1w[3], l1w[4], l1w[5], l1w[6], l1w[7], Wp1, bp1, 32);

    // CSR build (once; reused by both layers)
    zero_deg<<<(NN + 255) / 256, 256, 0, stream>>>(deg);
    hist_dst<<<(EE + 255) / 256, 256, 0, stream>>>(ei, deg);
    block_sum<<<NB, 256, 0, stream>>>(deg, partial);
    scan_partial<<<1, 64, 0, stream>>>(partial);
    block_scan<<<NB, 256, 0, stream>>>(deg, partial, roff, woff);
    scatter_edges<<<(EE + 255) / 256, 256, 0, stream>>>(ei, woff, esrc);

    const int RB = (NN + 127) / 128;             // 782
    const int gemm_blocks = 56 * ((RB + 7) / 8); // 5488, swizzle-bijective
    int attn_blocks = (NN * 64 + 255) / 256;     // one wave per node

    // layer 0
    gemm_qkvs<<<gemm_blocks, 256, 0, stream>>>(x, Wp0, bp0, qkvs, NN, 128);
    fused_attn<<<attn_blocks, 256, 0, stream>>>(qkvs, roff, esrc, h0);

    // layer 1
    gemm_qkvs<<<gemm_blocks, 256, 0, stream>>>(h0, Wp1, bp1, qkvs, NN, 32);
    fused_attn<<<attn_blocks, 256, 0, stream>>>(qkvs, roff, esrc, h0);

    // output linear
    out_linear<<<(NN * OUT_DIM + 255) / 256, 256, 0, stream>>>(h0, Wout, bout, out);
}

// Round 4
// 557.374 us; speedup vs baseline: 3.7462x; 1.1566x over previous
//
#include <hip/hip_runtime.h>
#include <math.h>

#define NN 100000
#define EE 800000
#define IN_DIM 128
#define HID 32
#define HEADS 4
#define QKV 128         // HEADS*HID
#define COLS 416        // 3*QKV + HID (q|k|v|skip)
#define QS_W 160        // q(128) + skip(32), fp32
#define KV_W 256        // k(128) + v(128), bf16
#define OUT_DIM 16
#define NB 98           // ceil(NN/1024) scan blocks

__device__ __forceinline__ unsigned short f2bf(float f) {
    unsigned int u = __float_as_uint(f);
    unsigned int r = (u + 0x7FFF + ((u >> 16) & 1)) >> 16;   // RNE
    return (unsigned short)r;
}
__device__ __forceinline__ float bf2f(unsigned short h) {
    return __uint_as_float((unsigned int)h << 16);
}

// ---------------- pack weights: Wp[K][416], bp[416] ----------------
__global__ void pack_w(const float* __restrict__ Wq, const float* __restrict__ bq,
                       const float* __restrict__ Wk, const float* __restrict__ bk,
                       const float* __restrict__ Wv, const float* __restrict__ bv,
                       const float* __restrict__ Ws, const float* __restrict__ bs,
                       float* __restrict__ Wp, float* __restrict__ bp, int K) {
    int idx = blockIdx.x * blockDim.x + threadIdx.x;
    int total = K * COLS;
    if (idx < total) {
        int k = idx / COLS;
        int j = idx - k * COLS;
        float v;
        if (j < 128)      v = Wq[k * 128 + j];
        else if (j < 256) v = Wk[k * 128 + (j - 128)];
        else if (j < 384) v = Wv[k * 128 + (j - 256)];
        else              v = Ws[k * 32 + (j - 384)];
        Wp[idx] = v;
    }
    if (idx < COLS) {
        float b;
        if (idx < 128)      b = bq[idx];
        else if (idx < 256) b = bk[idx - 128];
        else if (idx < 384) b = bv[idx - 256];
        else                b = bs[idx - 384];
        bp[idx] = b;
    }
}

// ---------------- CSR build ----------------
__global__ void zero_deg(int* __restrict__ deg) {
    int i = blockIdx.x * blockDim.x + threadIdx.x;
    if (i < NN) deg[i] = 0;
}

__global__ void hist_dst(const int* __restrict__ ei, int* __restrict__ deg) {
    int e = blockIdx.x * blockDim.x + threadIdx.x;
    if (e < EE) atomicAdd(&deg[ei[EE + e]], 1);
}

__global__ void block_sum(const int* __restrict__ deg, int* __restrict__ partial) {
    __shared__ int sdata[256];
    int b = blockIdx.x, t = threadIdx.x;
    int sum = 0;
    for (int i = t; i < 1024; i += 256) {
        int g = b * 1024 + i;
        if (g < NN) sum += deg[g];
    }
    sdata[t] = sum; __syncthreads();
    for (int s = 128; s > 0; s >>= 1) {
        if (t < s) sdata[t] += sdata[t + s];
        __syncthreads();
    }
    if (t == 0) partial[b] = sdata[0];
}

__global__ void scan_partial(int* __restrict__ partial) {
    if (blockIdx.x == 0 && threadIdx.x == 0) {
        int run = 0;
        for (int i = 0; i < NB; ++i) { int v = partial[i]; partial[i] = run; run += v; }
    }
}

__global__ void block_scan(const int* __restrict__ deg, const int* __restrict__ partial,
                           int* __restrict__ roff, int* __restrict__ woff) {
    __shared__ int ssum[256];
    int b = blockIdx.x, t = threadIdx.x;
    int base = b * 1024 + t * 4;
    int v[4]; int s = 0;
    #pragma unroll
    for (int i = 0; i < 4; ++i) {
        int g = base + i;
        v[i] = (g < NN) ? deg[g] : 0;
        s += v[i];
    }
    ssum[t] = s; __syncthreads();
    for (int off = 1; off < 256; off <<= 1) {
        int val = (t >= off) ? ssum[t - off] : 0;
        __syncthreads();
        ssum[t] += val;
        __syncthreads();
    }
    int excl = (t == 0) ? 0 : ssum[t - 1];
    excl += partial[b];
    #pragma unroll
    for (int i = 0; i < 4; ++i) {
        int g = base + i;
        if (g < NN) { roff[g] = excl; woff[g] = excl; }
        excl += v[i];
    }
    if (b == NB - 1 && t == 255) roff[NN] = EE;
}

__global__ void scatter_edges(const int* __restrict__ ei, int* __restrict__ woff,
                              int* __restrict__ esrc) {
    int e = blockIdx.x * blockDim.x + threadIdx.x;
    if (e < EE) {
        int dst = ei[EE + e];
        int pos = atomicAdd(&woff[dst], 1);
        esrc[pos] = ei[e];
    }
}

// ---------------- fused qkv+skip GEMM ----------------
// tile 128x64, block 256 = 16 row-groups x 16 col-groups, microtile 8x4.
// X tile stored TRANSPOSED in LDS, pad 130 (4*130 % 32 == 8 -> 2-way, free).
// XCD-aware swizzle keeps all 7 col-blocks of a row-block on one XCD.
// Epilogue: q,skip -> qs fp32 [N][160]; k,v -> kvb bf16 [N][256].
__global__ __launch_bounds__(256) void gemm_qkvs(
        const float* __restrict__ X, const float* __restrict__ Wp,
        const float* __restrict__ bp, float* __restrict__ qs,
        unsigned short* __restrict__ kvb, int Nrows, int K) {
    __shared__ float xs_t[32][130];   // [k][row], PAD=130: conflict-free stores
    __shared__ float wsm[32][64];     // [k][col]
    const int tid = threadIdx.x;
    const int tx = tid & 15;          // col group (4 cols)
    const int ty = tid >> 4;          // row group (8 rows)

    const int RB = (Nrows + 127) >> 7;
    int b = blockIdx.x;
    int r = (b & 7) + ((b / 56) << 3);
    int c = (b >> 3) % 7;
    if (r >= RB) return;
    const int m0 = r << 7;
    const int n0 = c << 6;

    float acc[8][4] = {};

    for (int kc = 0; kc < K; kc += 32) {
        #pragma unroll
        for (int i = 0; i < 4; ++i) {
            int lid = tid + i * 256;
            int rr = lid >> 3;         // 0..127
            int c4 = lid & 7;          // 0..7
            float4 xv = make_float4(0.f, 0.f, 0.f, 0.f);
            if (m0 + rr < Nrows)
                xv = *(const float4*)(X + (size_t)(m0 + rr) * K + kc + c4 * 4);
            int kk = c4 * 4;
            xs_t[kk + 0][rr] = xv.x;
            xs_t[kk + 1][rr] = xv.y;
            xs_t[kk + 2][rr] = xv.z;
            xs_t[kk + 3][rr] = xv.w;
        }
        #pragma unroll
        for (int i = 0; i < 2; ++i) {
            int lid = tid + i * 256;
            int kr = lid >> 4;
            int c4 = lid & 15;
            int col = n0 + c4 * 4;
            float4 wv = make_float4(0.f, 0.f, 0.f, 0.f);
            if (col < COLS)
                wv = *(const float4*)(Wp + (size_t)(kc + kr) * COLS + col);
            *(float4*)&wsm[kr][c4 * 4] = wv;
        }
        __syncthreads();
        #pragma unroll 8
        for (int k = 0; k < 32; ++k) {
            float4 xa = *(const float4*)&xs_t[k][ty * 8];
            float4 xb = *(const float4*)&xs_t[k][ty * 8 + 4];
            float4 wv = *(const float4*)&wsm[k][tx * 4];
            float xr[8] = {xa.x, xa.y, xa.z, xa.w, xb.x, xb.y, xb.z, xb.w};
            #pragma unroll
            for (int i = 0; i < 8; ++i) {
                acc[i][0] += xr[i] * wv.x;
                acc[i][1] += xr[i] * wv.y;
                acc[i][2] += xr[i] * wv.z;
                acc[i][3] += xr[i] * wv.w;
            }
        }
        __syncthreads();
    }

    const int col = n0 + tx * 4;
    if (col >= COLS) return;
    float4 bv = *(const float4*)(bp + col);
    #pragma unroll
    for (int i = 0; i < 8; ++i) {
        int row = m0 + ty * 8 + i;
        if (row >= Nrows) break;
        float o0 = acc[i][0] + bv.x;
        float o1 = acc[i][1] + bv.y;
        float o2 = acc[i][2] + bv.z;
        float o3 = acc[i][3] + bv.w;
        if (col < 128) {                       // q -> fp32
            *(float4*)(qs + (size_t)row * QS_W + col) = make_float4(o0, o1, o2, o3);
        } else if (col < 256) {                // k -> bf16
            ushort4 u = {f2bf(o0), f2bf(o1), f2bf(o2), f2bf(o3)};
            *(ushort4*)(kvb + (size_t)row * KV_W + (col - 128)) = u;
        } else if (col < 384) {                // v -> bf16
            ushort4 u = {f2bf(o0), f2bf(o1), f2bf(o2), f2bf(o3)};
            *(ushort4*)(kvb + (size_t)row * KV_W + 128 + (col - 256)) = u;
        } else {                               // skip -> fp32
            *(float4*)(qs + (size_t)row * QS_W + 128 + (col - 384)) = make_float4(o0, o1, o2, o3);
        }
    }
}

// ---------------- fused attention: one wave per dst node ----------------
// lanes 0..31: q fragment (float4); lanes 32..63: v accumulator.
// k|v gathered as bf16 (ushort4 = 8 B/lane = 512 B/edge).
#define ATTN_STEP(kv)  {                                                     \
    float part = q4.x * (kv).x + q4.y * (kv).y + q4.z * (kv).z + q4.w * (kv).w; \
    part += __shfl_xor(part, 1);                                             \
    part += __shfl_xor(part, 2);                                             \
    part += __shfl_xor(part, 4);                                             \
    float a = __shfl(part, hsrc) * 0.17677669529663687f;                     \
    float mn = fmaxf(m, a);                                                  \
    float corr = __expf(m - mn);                                             \
    float p = __expf(a - mn);                                                \
    s = s * corr + p;                                                        \
    acc.x = acc.x * corr + p * (kv).x;                                       \
    acc.y = acc.y * corr + p * (kv).y;                                       \
    acc.z = acc.z * corr + p * (kv).z;                                       \
    acc.w = acc.w * corr + p * (kv).w;                                       \
    m = mn; }

__device__ __forceinline__ float4 ld_kv(const unsigned short* __restrict__ kvb,
                                        int src, int lane) {
    ushort4 t = *(const ushort4*)(kvb + (size_t)src * KV_W + 4 * lane);
    return make_float4(bf2f(t.x), bf2f(t.y), bf2f(t.z), bf2f(t.w));
}

__global__ __launch_bounds__(256) void fused_attn(
        const float* __restrict__ qs, const unsigned short* __restrict__ kvb,
        const int* __restrict__ roff, const int* __restrict__ esrc,
        float* __restrict__ hout) {
    const int lane = threadIdx.x & 63;
    const int w = (blockIdx.x * blockDim.x + threadIdx.x) >> 6;
    if (w >= NN) return;
    const int n = w;
    const int kl = lane & 31;
    const int hsrc = kl & 24;                 // leader lane of this head group
    const float* row = qs + (size_t)n * QS_W;
    const float* qaddr = (lane < 32) ? (row + 4 * kl) : (row + 128 + 4 * (kl & 7));
    float4 q4 = *(const float4*)qaddr;

    float m = -INFINITY, s = 0.f;
    float4 acc = make_float4(0.f, 0.f, 0.f, 0.f);
    const int e0 = roff[n], e1 = roff[n + 1];
    int e = e0;
    for (; e + 4 <= e1; e += 4) {
        int s0 = esrc[e], s1 = esrc[e + 1], s2 = esrc[e + 2], s3 = esrc[e + 3];
        float4 kv0 = ld_kv(kvb, s0, lane);
        float4 kv1 = ld_kv(kvb, s1, lane);
        float4 kv2 = ld_kv(kvb, s2, lane);
        float4 kv3 = ld_kv(kvb, s3, lane);
        ATTN_STEP(kv0); ATTN_STEP(kv1); ATTN_STEP(kv2); ATTN_STEP(kv3);
    }
    for (; e < e1; ++e) {
        float4 kv = ld_kv(kvb, esrc[e], lane);
        ATTN_STEP(kv);
    }
    float inv = (s > 0.f) ? 1.f / s : 0.f;
    float4 o;
    o.x = acc.x * inv; o.y = acc.y * inv; o.z = acc.z * inv; o.w = acc.w * inv;
    // sum over heads (head bits of kl are bits 3,4)
    o.x += __shfl_xor(o.x, 8);  o.y += __shfl_xor(o.y, 8);  o.z += __shfl_xor(o.z, 8);  o.w += __shfl_xor(o.w, 8);
    o.x += __shfl_xor(o.x, 16); o.y += __shfl_xor(o.y, 16); o.z += __shfl_xor(o.z, 16); o.w += __shfl_xor(o.w, 16);
    if (lane >= 32 && lane < 40) {
        float4 rr;
        rr.x = fmaxf(o.x * 0.25f + q4.x, 0.f);   // q4 holds skip in these lanes
        rr.y = fmaxf(o.y * 0.25f + q4.y, 0.f);
        rr.z = fmaxf(o.z * 0.25f + q4.z, 0.f);
        rr.w = fmaxf(o.w * 0.25f + q4.w, 0.f);
        *(float4*)(hout + (size_t)n * HID + 4 * (lane - 32)) = rr;
    }
}

// ---------------- final linear: out = h @ Wout + bout --------------------
__global__ void out_linear(const float* __restrict__ h, const float* __restrict__ Wout,
                           const float* __restrict__ bout, float* __restrict__ out) {
    int idx = blockIdx.x * blockDim.x + threadIdx.x;
    if (idx >= NN * OUT_DIM) return;
    int n = idx >> 4;
    int j = idx & 15;
    float accv = bout[j];
    #pragma unroll
    for (int k = 0; k < HID; ++k)
        accv += h[(size_t)n * HID + k] * Wout[k * OUT_DIM + j];
    out[idx] = accv;
}

extern "C" void kernel_launch(void* const* d_in, const int* in_sizes, int n_in,
                              void* d_out, int out_size, void* d_ws, size_t ws_size,
                              hipStream_t stream) {
    const float* x  = (const float*)d_in[0];
    const int*   ei = (const int*)d_in[1];
    const float* l0w[8]; const float* l1w[8];
    for (int i = 0; i < 8; ++i) { l0w[i] = (const float*)d_in[2 + i]; l1w[i] = (const float*)d_in[10 + i]; }
    const float* Wout = (const float*)d_in[18];
    const float* bout = (const float*)d_in[19];
    float* out = (float*)d_out;

    // workspace layout
    float* ws = (float*)d_ws;
    float* qs   = ws;                           // NN*160 floats
    float* h0   = qs + (size_t)NN * QS_W;       // NN*32
    float* Wp0  = h0 + (size_t)NN * HID;        // 128*416
    float* bp0  = Wp0 + 128 * COLS;             // 416
    float* Wp1  = bp0 + COLS;                   // 32*416
    float* bp1  = Wp1 + 32 * COLS;              // 416
    unsigned short* kvb = (unsigned short*)(bp1 + COLS);   // NN*256 bf16 (8B-aligned)
    int* ibase  = (int*)(kvb + (size_t)NN * KV_W);
    int* deg     = ibase;                       // NN
    int* roff    = deg + NN;                    // NN+1
    int* woff    = roff + NN + 1;               // NN
    int* partial = woff + NN;                   // NB
    int* esrc    = partial + NB;                // EE

    // pack weights
    pack_w<<<(128 * COLS + 255) / 256, 256, 0, stream>>>(
        l0w[0], l0w[1], l0w[2], l0w[3], l0w[4], l0w[5], l0w[6], l0w[7], Wp0, bp0, 128);
    pack_w<<<(32 * COLS + 255) / 256, 256, 0, stream>>>(
        l1w[0], l1w[1], l1w[2], l1w[3], l1w[4], l1w[5], l1w[6], l1w[7], Wp1, bp1, 32);

    // CSR build (once; reused by both layers)
    zero_deg<<<(NN + 255) / 256, 256, 0, stream>>>(deg);
    hist_dst<<<(EE + 255) / 256, 256, 0, stream>>>(ei, deg);
    block_sum<<<NB, 256, 0, stream>>>(deg, partial);
    scan_partial<<<1, 64, 0, stream>>>(partial);
    block_scan<<<NB, 256, 0, stream>>>(deg, partial, roff, woff);
    scatter_edges<<<(EE + 255) / 256, 256, 0, stream>>>(ei, woff, esrc);

    const int RB = (NN + 127) / 128;             // 782
    const int gemm_blocks = 56 * ((RB + 7) / 8); // swizzle-bijective
    int attn_blocks = (NN * 64 + 255) / 256;     // one wave per node

    // layer 0
    gemm_qkvs<<<gemm_blocks, 256, 0, stream>>>(x, Wp0, bp0, qs, kvb, NN, 128);
    fused_attn<<<attn_blocks, 256, 0, stream>>>(qs, kvb, roff, esrc, h0);

    // layer 1
    gemm_qkvs<<<gemm_blocks, 256, 0, stream>>>(h0, Wp1, bp1, qs, kvb, NN, 32);
    fused_attn<<<attn_blocks, 256, 0, stream>>>(qs, kvb, roff, esrc, h0);

    // output linear
    out_linear<<<(NN * OUT_DIM + 255) / 256, 256, 0, stream>>>(h0, Wout, bout, out);
}